// Round 1
// baseline (11196.713 us; speedup 1.0000x reference)
//
#include <hip/hip_runtime.h>
#include <hip/hip_bf16.h>

// GRU: V=50000, E=256, H=256, B=64, T=512
// inputs: input[B,T] int32, embedding[V,E] f32, W_ih[3H,E] f32, W_hh[3H,H] f32,
//         b_ih[3H] f32, b_hh[3H] f32
// out: outputs[T,B,H] f32 then h_last[1,B,H] f32 (concat flat)

#define T_SEQ 512
#define B_SZ 64
#define E_DIM 256
#define H_DIM 256
#define G3 768   // 3*H

// ---------------- Kernel A: x_proj = gather(emb, input) @ W_ih^T + b_ih ----
// C[M=T*B, N=768], K=256.  Row m = t*64 + b; gather row = input[b*512 + t].
// 64x64 tile, 256 threads, 4x4 micro-tile, BK=32.
#define BM 64
#define BN 64
#define BK 32
#define LDSPAD 4   // row stride 36 floats = 144B, 16B-aligned for float4

__global__ __launch_bounds__(256) void xproj_kernel(
    const int* __restrict__ input,
    const float* __restrict__ emb,
    const float* __restrict__ W_ih,
    const float* __restrict__ b_ih,
    float* __restrict__ xp)
{
    __shared__ float As[BM][BK + LDSPAD];
    __shared__ float Bs[BN][BK + LDSPAD];
    __shared__ int rowidx[BM];

    const int tid = threadIdx.x;
    const int m0 = blockIdx.x * BM;   // 512 tiles
    const int n0 = blockIdx.y * BN;   // 12 tiles

    if (tid < BM) {
        int m = m0 + tid;
        int t = m >> 6;         // m / 64
        int b = m & 63;
        rowidx[tid] = input[b * T_SEQ + t];
    }
    __syncthreads();

    float acc[4][4] = {};
    const int ty = tid >> 4;   // 0..15
    const int tx = tid & 15;   // 0..15

    for (int k0 = 0; k0 < E_DIM; k0 += BK) {
        // stage A: 64 rows x 32 cols = 512 float4; thread loads 2
        #pragma unroll
        for (int i = 0; i < 2; ++i) {
            int f4 = tid * 2 + i;
            int row = f4 >> 3;
            int c4  = (f4 & 7) * 4;
            float4 v = *reinterpret_cast<const float4*>(
                emb + (size_t)rowidx[row] * E_DIM + k0 + c4);
            *reinterpret_cast<float4*>(&As[row][c4]) = v;
        }
        // stage B: W_ih rows n0..n0+63
        #pragma unroll
        for (int i = 0; i < 2; ++i) {
            int f4 = tid * 2 + i;
            int row = f4 >> 3;
            int c4  = (f4 & 7) * 4;
            float4 v = *reinterpret_cast<const float4*>(
                W_ih + (size_t)(n0 + row) * E_DIM + k0 + c4);
            *reinterpret_cast<float4*>(&Bs[row][c4]) = v;
        }
        __syncthreads();

        #pragma unroll
        for (int kk = 0; kk < BK; kk += 4) {
            float4 a[4], b[4];
            #pragma unroll
            for (int i = 0; i < 4; ++i)
                a[i] = *reinterpret_cast<const float4*>(&As[ty * 4 + i][kk]);
            #pragma unroll
            for (int j = 0; j < 4; ++j)
                b[j] = *reinterpret_cast<const float4*>(&Bs[tx * 4 + j][kk]);
            #pragma unroll
            for (int i = 0; i < 4; ++i)
                #pragma unroll
                for (int j = 0; j < 4; ++j)
                    acc[i][j] += a[i].x * b[j].x + a[i].y * b[j].y +
                                 a[i].z * b[j].z + a[i].w * b[j].w;
        }
        __syncthreads();
    }

    // epilogue: add bias, float4 stores (cols are consecutive per thread)
    #pragma unroll
    for (int i = 0; i < 4; ++i) {
        int m = m0 + ty * 4 + i;
        int n = n0 + tx * 4;
        float4 o;
        o.x = acc[i][0] + b_ih[n + 0];
        o.y = acc[i][1] + b_ih[n + 1];
        o.z = acc[i][2] + b_ih[n + 2];
        o.w = acc[i][3] + b_ih[n + 3];
        *reinterpret_cast<float4*>(&xp[(size_t)m * G3 + n]) = o;
    }
}

// ---------------- Kernel B: sequential GRU scan, one block per batch ------
// Thread j owns h[j]; computes hp rows j, j+256, j+512 each step.
__global__ __launch_bounds__(256) void gru_seq_kernel(
    const float* __restrict__ xp,    // [T*B, 768]
    const float* __restrict__ W_hh,  // [768, 256]
    const float* __restrict__ b_hh,  // [768]
    float* __restrict__ out)         // outputs [T*B*256] ++ h_last [64*256]
{
    const int b = blockIdx.x;     // 0..63
    const int j = threadIdx.x;    // 0..255

    __shared__ float hs[H_DIM];
    hs[j] = 0.0f;
    float h = 0.0f;

    const float bhr = b_hh[j];
    const float bhz = b_hh[H_DIM + j];
    const float bhn = b_hh[2 * H_DIM + j];

    const float4* __restrict__ Wr =
        reinterpret_cast<const float4*>(W_hh + (size_t)j * H_DIM);
    const float4* __restrict__ Wz =
        reinterpret_cast<const float4*>(W_hh + (size_t)(H_DIM + j) * H_DIM);
    const float4* __restrict__ Wn =
        reinterpret_cast<const float4*>(W_hh + (size_t)(2 * H_DIM + j) * H_DIM);

    __syncthreads();

    for (int t = 0; t < T_SEQ; ++t) {
        const size_t m = (size_t)t * B_SZ + b;
        const float xr = xp[m * G3 + j];
        const float xz = xp[m * G3 + H_DIM + j];
        const float xn = xp[m * G3 + 2 * H_DIM + j];

        float hr = bhr, hz = bhz, hn = bhn;
        const float4* h4 = reinterpret_cast<const float4*>(hs);
        #pragma unroll 4
        for (int k4 = 0; k4 < H_DIM / 4; ++k4) {
            const float4 hv = h4[k4];
            const float4 wr = Wr[k4];
            const float4 wz = Wz[k4];
            const float4 wn = Wn[k4];
            hr += wr.x * hv.x + wr.y * hv.y + wr.z * hv.z + wr.w * hv.w;
            hz += wz.x * hv.x + wz.y * hv.y + wz.z * hv.z + wz.w * hv.w;
            hn += wn.x * hv.x + wn.y * hv.y + wn.z * hv.z + wn.w * hv.w;
        }

        const float r = 1.0f / (1.0f + expf(-(xr + hr)));
        const float z = 1.0f / (1.0f + expf(-(xz + hz)));
        const float n = tanhf(xn + r * hn);
        const float hnew = (1.0f - z) * n + z * h;

        out[m * H_DIM + j] = hnew;

        __syncthreads();          // all dot-products done reading hs
        hs[j] = hnew;
        h = hnew;
        __syncthreads();          // hs updated for next step
    }

    out[(size_t)T_SEQ * B_SZ * H_DIM + (size_t)b * H_DIM + j] = h;
}

extern "C" void kernel_launch(void* const* d_in, const int* in_sizes, int n_in,
                              void* d_out, int out_size, void* d_ws, size_t ws_size,
                              hipStream_t stream) {
    const int*   input = (const int*)d_in[0];
    const float* emb   = (const float*)d_in[1];
    const float* W_ih  = (const float*)d_in[2];
    const float* W_hh  = (const float*)d_in[3];
    const float* b_ih  = (const float*)d_in[4];
    const float* b_hh  = (const float*)d_in[5];
    float* out = (float*)d_out;

    float* xp = (float*)d_ws;   // [T*B, 768] = 100,663,296 bytes

    dim3 gridA(T_SEQ * B_SZ / BM, G3 / BN);   // (512, 12)
    xproj_kernel<<<gridA, 256, 0, stream>>>(input, emb, W_ih, b_ih, xp);

    gru_seq_kernel<<<B_SZ, 256, 0, stream>>>(xp, W_hh, b_hh, out);
}

// Round 2
// 947.646 us; speedup vs baseline: 11.8153x; 11.8153x over previous
//
#include <hip/hip_runtime.h>
#include <hip/hip_bf16.h>

// GRU: V=50000, E=256, H=256, B=64, T=512
// out: outputs[T,B,H] f32 then h_last[1,B,H] f32 (concat flat)

#define T_SEQ 512
#define B_SZ 64
#define E_DIM 256
#define H_DIM 256
#define G3 768   // 3*H

typedef _Float16 half2v __attribute__((ext_vector_type(2)));

#if __has_builtin(__builtin_amdgcn_fdot2)
#define FDOT2(a, b, c) __builtin_amdgcn_fdot2((a), (b), (c), false)
#else
#define FDOT2(a, b, c) ((c) + (float)(a).x * (float)(b).x + (float)(a).y * (float)(b).y)
#endif

// ---------------- Kernel A: x_proj = gather(emb, input) @ W_ih^T + b_ih ----
#define BM 64
#define BN 64
#define BK 32
#define LDSPAD 4

__global__ __launch_bounds__(256) void xproj_kernel(
    const int* __restrict__ input,
    const float* __restrict__ emb,
    const float* __restrict__ W_ih,
    const float* __restrict__ b_ih,
    float* __restrict__ xp)
{
    __shared__ float As[BM][BK + LDSPAD];
    __shared__ float Bs[BN][BK + LDSPAD];
    __shared__ int rowidx[BM];

    const int tid = threadIdx.x;
    const int m0 = blockIdx.x * BM;
    const int n0 = blockIdx.y * BN;

    if (tid < BM) {
        int m = m0 + tid;
        int t = m >> 6;
        int b = m & 63;
        rowidx[tid] = input[b * T_SEQ + t];
    }
    __syncthreads();

    float acc[4][4] = {};
    const int ty = tid >> 4;
    const int tx = tid & 15;

    for (int k0 = 0; k0 < E_DIM; k0 += BK) {
        #pragma unroll
        for (int i = 0; i < 2; ++i) {
            int f4 = tid * 2 + i;
            int row = f4 >> 3;
            int c4  = (f4 & 7) * 4;
            float4 v = *reinterpret_cast<const float4*>(
                emb + (size_t)rowidx[row] * E_DIM + k0 + c4);
            *reinterpret_cast<float4*>(&As[row][c4]) = v;
        }
        #pragma unroll
        for (int i = 0; i < 2; ++i) {
            int f4 = tid * 2 + i;
            int row = f4 >> 3;
            int c4  = (f4 & 7) * 4;
            float4 v = *reinterpret_cast<const float4*>(
                W_ih + (size_t)(n0 + row) * E_DIM + k0 + c4);
            *reinterpret_cast<float4*>(&Bs[row][c4]) = v;
        }
        __syncthreads();

        #pragma unroll
        for (int kk = 0; kk < BK; kk += 4) {
            float4 a[4], b[4];
            #pragma unroll
            for (int i = 0; i < 4; ++i)
                a[i] = *reinterpret_cast<const float4*>(&As[ty * 4 + i][kk]);
            #pragma unroll
            for (int j = 0; j < 4; ++j)
                b[j] = *reinterpret_cast<const float4*>(&Bs[tx * 4 + j][kk]);
            #pragma unroll
            for (int i = 0; i < 4; ++i)
                #pragma unroll
                for (int j = 0; j < 4; ++j)
                    acc[i][j] += a[i].x * b[j].x + a[i].y * b[j].y +
                                 a[i].z * b[j].z + a[i].w * b[j].w;
        }
        __syncthreads();
    }

    #pragma unroll
    for (int i = 0; i < 4; ++i) {
        int m = m0 + ty * 4 + i;
        int n = n0 + tx * 4;
        float4 o;
        o.x = acc[i][0] + b_ih[n + 0];
        o.y = acc[i][1] + b_ih[n + 1];
        o.z = acc[i][2] + b_ih[n + 2];
        o.w = acc[i][3] + b_ih[n + 3];
        *reinterpret_cast<float4*>(&xp[(size_t)m * G3 + n]) = o;
    }
}

// ---------------- Kernel B: GRU scan, weights resident in registers -------
// 64 blocks (one per batch element), 1024 threads = 16 waves.
// Thread (j = tid&255, q = tid>>8): holds W_hh rows {j, j+256, j+512},
// k-slice [64q, 64q+64) as 96 packed-f16 VGPRs. h broadcast via 512B LDS.
__global__ __launch_bounds__(1024) void gru_scan_kernel(
    const float* __restrict__ xp,    // [T*B, 768]
    const float* __restrict__ W_hh,  // [768, 256]
    const float* __restrict__ b_hh,  // [768]
    float* __restrict__ out)         // outputs [T*B*256] ++ h_last [64*256]
{
    const int b   = blockIdx.x;    // batch element
    const int tid = threadIdx.x;
    const int j   = tid & 255;     // output column within H
    const int q   = tid >> 8;      // k-slice 0..3

    __shared__ __align__(16) _Float16 hsArr[H_DIM];       // h as f16
    __shared__ float hpQ[3][H_DIM][4];                    // per-q partials

    // ---- prologue: load + convert this thread's weight slice to f16 ----
    half2v w0[32], w1[32], w2[32];
    {
        const float* r0 = W_hh + (size_t)(j)           * H_DIM + q * 64;
        const float* r1 = W_hh + (size_t)(H_DIM + j)   * H_DIM + q * 64;
        const float* r2 = W_hh + (size_t)(2*H_DIM + j) * H_DIM + q * 64;
        #pragma unroll
        for (int k2 = 0; k2 < 32; ++k2) {
            float2 f0 = reinterpret_cast<const float2*>(r0)[k2];
            float2 f1 = reinterpret_cast<const float2*>(r1)[k2];
            float2 f2 = reinterpret_cast<const float2*>(r2)[k2];
            w0[k2] = half2v{(_Float16)f0.x, (_Float16)f0.y};
            w1[k2] = half2v{(_Float16)f1.x, (_Float16)f1.y};
            w2[k2] = half2v{(_Float16)f2.x, (_Float16)f2.y};
        }
    }
    // bias folded into q==0's accumulator init
    const float bias0 = (q == 0) ? b_hh[j]             : 0.0f;
    const float bias1 = (q == 0) ? b_hh[H_DIM + j]     : 0.0f;
    const float bias2 = (q == 0) ? b_hh[2*H_DIM + j]   : 0.0f;

    if (tid < H_DIM) hsArr[tid] = (_Float16)0.0f;
    float h = 0.0f;   // live in q==0 lanes
    __syncthreads();

    const uint4* hsp = reinterpret_cast<const uint4*>(hsArr) + q * 8; // 64 halves

    for (int t = 0; t < T_SEQ; ++t) {
        // xp loads for this step (q==0 lanes); latency covered by dot phase
        float xr = 0.f, xz = 0.f, xn = 0.f;
        if (q == 0) {
            const float* x0 = xp + ((size_t)t * B_SZ + b) * G3 + j;
            xr = x0[0];
            xz = x0[H_DIM];
            xn = x0[2 * H_DIM];
        }

        // ---- partial dots over this thread's 64-wide k slice ----
        float acc0 = bias0, acc1 = bias1, acc2 = bias2;
        #pragma unroll
        for (int k8 = 0; k8 < 8; ++k8) {
            uint4 hv = hsp[k8];                     // 8 halves (broadcast read)
            half2v h2a = __builtin_bit_cast(half2v, hv.x);
            half2v h2b = __builtin_bit_cast(half2v, hv.y);
            half2v h2c = __builtin_bit_cast(half2v, hv.z);
            half2v h2d = __builtin_bit_cast(half2v, hv.w);
            acc0 = FDOT2(w0[k8*4+0], h2a, acc0);
            acc1 = FDOT2(w1[k8*4+0], h2a, acc1);
            acc2 = FDOT2(w2[k8*4+0], h2a, acc2);
            acc0 = FDOT2(w0[k8*4+1], h2b, acc0);
            acc1 = FDOT2(w1[k8*4+1], h2b, acc1);
            acc2 = FDOT2(w2[k8*4+1], h2b, acc2);
            acc0 = FDOT2(w0[k8*4+2], h2c, acc0);
            acc1 = FDOT2(w1[k8*4+2], h2c, acc1);
            acc2 = FDOT2(w2[k8*4+2], h2c, acc2);
            acc0 = FDOT2(w0[k8*4+3], h2d, acc0);
            acc1 = FDOT2(w1[k8*4+3], h2d, acc1);
            acc2 = FDOT2(w2[k8*4+3], h2d, acc2);
        }
        hpQ[0][j][q] = acc0;
        hpQ[1][j][q] = acc1;
        hpQ[2][j][q] = acc2;
        __syncthreads();   // partials visible; all hsArr reads done

        if (q == 0) {
            float hr = acc0 + hpQ[0][j][1] + hpQ[0][j][2] + hpQ[0][j][3];
            float hz = acc1 + hpQ[1][j][1] + hpQ[1][j][2] + hpQ[1][j][3];
            float hn = acc2 + hpQ[2][j][1] + hpQ[2][j][2] + hpQ[2][j][3];

            const float r = 1.0f / (1.0f + __expf(-(xr + hr)));
            const float z = 1.0f / (1.0f + __expf(-(xz + hz)));
            const float n = tanhf(xn + r * hn);
            const float hnew = (1.0f - z) * n + z * h;
            h = hnew;

            out[((size_t)t * B_SZ + b) * H_DIM + j] = hnew;
            hsArr[j] = (_Float16)hnew;
        }
        __syncthreads();   // hsArr(t+1) ready
    }

    if (q == 0)
        out[(size_t)T_SEQ * B_SZ * H_DIM + (size_t)b * H_DIM + j] = h;
}

extern "C" void kernel_launch(void* const* d_in, const int* in_sizes, int n_in,
                              void* d_out, int out_size, void* d_ws, size_t ws_size,
                              hipStream_t stream) {
    const int*   input = (const int*)d_in[0];
    const float* emb   = (const float*)d_in[1];
    const float* W_ih  = (const float*)d_in[2];
    const float* W_hh  = (const float*)d_in[3];
    const float* b_ih  = (const float*)d_in[4];
    const float* b_hh  = (const float*)d_in[5];
    float* out = (float*)d_out;

    float* xp = (float*)d_ws;   // [T*B, 768] floats

    dim3 gridA(T_SEQ * B_SZ / BM, G3 / BN);   // (512, 12)
    xproj_kernel<<<gridA, 256, 0, stream>>>(input, emb, W_ih, b_ih, xp);

    gru_scan_kernel<<<B_SZ, 1024, 0, stream>>>(xp, W_hh, b_hh, out);
}